// Round 15
// baseline (419.572 us; speedup 1.0000x reference)
//
#include <hip/hip_runtime.h>

#define B_ 2
#define S_ 2048
#define D_ 2048
#define H_ 16
#define DH_ 128

typedef __bf16 bf16_8 __attribute__((ext_vector_type(8)));
typedef __bf16 bf16_4 __attribute__((ext_vector_type(4)));
typedef float f32x4 __attribute__((ext_vector_type(4)));

__device__ __forceinline__ f32x4 mfma16(bf16_8 a, bf16_8 b, f32x4 c) {
  return __builtin_amdgcn_mfma_f32_16x16x32_bf16(a, b, c, 0, 0, 0);
}

__device__ __forceinline__ bf16_8 load8(const float* p) {
  f32x4 a = *(const f32x4*)p;
  f32x4 b = *(const f32x4*)(p + 4);
  bf16_8 r;
  r[0] = (__bf16)a[0]; r[1] = (__bf16)a[1]; r[2] = (__bf16)a[2]; r[3] = (__bf16)a[3];
  r[4] = (__bf16)b[0]; r[5] = (__bf16)b[1]; r[6] = (__bf16)b[2]; r[7] = (__bf16)b[3];
  return r;
}

// async global->LDS, 16B/lane, wave-uniform LDS base (HW adds lane*16)
__device__ __forceinline__ void async16(const __bf16* g, __bf16* l) {
  __builtin_amdgcn_global_load_lds(
      (const __attribute__((address_space(1))) void*)g,
      (__attribute__((address_space(3))) void*)l, 16, 0, 0);
}

// f32->bf16 convert: x (2 chunks) + 4 weights (1 chunk each).
__global__ __launch_bounds__(256) void cvt_all(
    const float* __restrict__ x, const float* __restrict__ wq,
    const float* __restrict__ wk, const float* __restrict__ wv,
    const float* __restrict__ wo, __bf16* __restrict__ xb,
    __bf16* __restrict__ wqb, __bf16* __restrict__ wkb,
    __bf16* __restrict__ wvb, __bf16* __restrict__ wob)
{
  const int W8 = (D_ * D_) / 8;   // 2^19
  int i = blockIdx.x * 256 + threadIdx.x;
  if (i < 2 * W8) {
    *(bf16_8*)(xb + (size_t)i * 8) = load8(x + (size_t)i * 8);
  } else {
    int j = i - 2 * W8;
    int sel = j >> 19, off = j & (W8 - 1);
    const float* s = sel == 0 ? wq : sel == 1 ? wk : sel == 2 ? wv : wo;
    __bf16* d = sel == 0 ? wqb : sel == 1 ? wkb : sel == 2 ? wvb : wob;
    *(bf16_8*)(d + (size_t)off * 8) = load8(s + (size_t)off * 8);
  }
}

// ============================================================================
// qkv_gemm8: 256x256 pipelined GEMM, 512 threads, 2-barrier group schedule.
// Round-15: collapsed the 4-sub-phase/8-barrier group (round-14: MfmaUtil 32%,
// reads->barrier->MFMA serialized per phase with only 1 block/CU at 128 KB
// LDS) into ONE read burst + ONE MFMA cluster per K-group:
//   [reads af0,b0 (12) -> b1 (4) -> af1 (8)] lgkmcnt(0) BARRIER
//   stage(g+2) (8 loads, into just-read current buffer)
//   64 MFMA unbroken (setprio) -- staging latency hides under it
//   vmcnt(8) BARRIER   (buffer g+1 landed & visible)
// vmcnt ledger: prologue stage(0)+stage(1)=16 -> vmcnt(8)=stage(0) landed.
// Steady state end-of-iter outstanding = stage(g+1)8 + stage(g+2)8 = 16 ->
// vmcnt(8) = stage(g+1) landed. Tail: g=30 -> vmcnt(0); g=31 -> none.
// Staging hazard: stage(g+2) overwrites current buffer's slots, whose last
// reads (this group's top) are all before the intervening barrier. Stage
// writes target the opposite buffer of the one MFMA reads? No -- MFMA reads
// REGISTERS only; LDS reads all complete pre-barrier. Safe.
// Reads live in regs: VGPR is free headroom (LDS caps at 1 block/CU anyway).
// ============================================================================
__global__ __launch_bounds__(512, 2) void qkv_gemm8(
    const __bf16* __restrict__ A,
    const __bf16* __restrict__ wqb, const __bf16* __restrict__ wkb,
    const __bf16* __restrict__ wvb,
    const float* __restrict__ fc, const float* __restrict__ fs,
    __bf16* __restrict__ Qo, __bf16* __restrict__ Ko, __bf16* __restrict__ Vo)
{
  __shared__ __align__(16) __bf16 smem8[65536];   // 128 KB
  const int tid = threadIdx.x;
  const int wave = tid >> 6, lane = tid & 63;
  const int quad = lane >> 4, l16 = lane & 15;
  const int wsm64 = (wave & 1) * 64;     // wave slice rows within quadrant
  const int wsn32 = (wave >> 1) * 32;    // wave slice cols within quadrant
  const int m0 = blockIdx.y * 256, n0 = blockIdx.x * 256;
  const int wsel = n0 >> 11, nloc = n0 & 2047;
  const __bf16* Wb = wsel == 0 ? wqb : wsel == 1 ? wkb : wvb;

  // staging: lane covers row (wave*8 + lane/8), swizzled col chunk (lane&7)^(lane>>3)
  const int srow = wave * 8 + (lane >> 3);
  const int scol = ((lane & 7) ^ (lane >> 3)) * 8;
  const __bf16* agl = A  + (size_t)(m0 + srow) * 2048 + scol;
  const __bf16* wgl = Wb + (size_t)(nloc + srow) * 2048 + scol;
  const int ldso = wave * 8 * 64;   // wave-uniform dest offset within a 64-row region

  const int colx0 = (quad * 8) ^ ((l16 & 7) * 8);
  const int colx1 = colx0 ^ 32;

  f32x4 acc[4][4][2] = {};

  auto SA8 = [&](int kt, int h, int q) {
    async16(agl + (size_t)(h * 128 + q * 64) * 2048 + (size_t)kt * 64,
            smem8 + (kt & 1) * 16384 + (h * 128 + q * 64) * 64 + ldso);
  };
  auto SB8 = [&](int kt, int h, int q) {
    async16(wgl + (size_t)(h * 128 + q * 64) * 2048 + (size_t)kt * 64,
            smem8 + 32768 + (kt & 1) * 16384 + (h * 128 + q * 64) * 64 + ldso);
  };
  auto STAGE_GRP = [&](int kt) {   // all 8 loads of K-group kt
    SA8(kt, 0, 0); SA8(kt, 0, 1); SA8(kt, 1, 0); SA8(kt, 1, 1);
    SB8(kt, 0, 0); SB8(kt, 0, 1); SB8(kt, 1, 0); SB8(kt, 1, 1);
  };

  // prologue: stage group 0 and group 1 (16 loads), wait group 0
  STAGE_GRP(0);
  STAGE_GRP(1);
  asm volatile("s_waitcnt vmcnt(8)" ::: "memory");   // group 0 landed
  __builtin_amdgcn_s_barrier();
  asm volatile("" ::: "memory");

  const int nG = 2048 / 64;   // 32
  for (int g = 0; g < nG; ++g) {
    const __bf16* Ab = smem8 + (g & 1) * 16384;
    const __bf16* Bb = smem8 + 32768 + (g & 1) * 16384;
    bf16_8 af0[4][2], af1[4][2], b0[2][2], b1[2][2];

    // read burst: af0+b0 first (MM0 operands), then b1, then af1
#pragma unroll
    for (int mi = 0; mi < 4; ++mi) {
      const __bf16* ap = Ab + (wsm64 + mi * 16 + l16) * 64;
      af0[mi][0] = *(const bf16_8*)(ap + colx0);
      af0[mi][1] = *(const bf16_8*)(ap + colx1);
    }
#pragma unroll
    for (int ni = 0; ni < 2; ++ni) {
      const __bf16* bp = Bb + (wsn32 + ni * 16 + l16) * 64;
      b0[ni][0] = *(const bf16_8*)(bp + colx0);
      b0[ni][1] = *(const bf16_8*)(bp + colx1);
    }
#pragma unroll
    for (int ni = 0; ni < 2; ++ni) {
      const __bf16* bp = Bb + (128 + wsn32 + ni * 16 + l16) * 64;
      b1[ni][0] = *(const bf16_8*)(bp + colx0);
      b1[ni][1] = *(const bf16_8*)(bp + colx1);
    }
#pragma unroll
    for (int mi = 0; mi < 4; ++mi) {
      const __bf16* ap = Ab + (128 + wsm64 + mi * 16 + l16) * 64;
      af1[mi][0] = *(const bf16_8*)(ap + colx0);
      af1[mi][1] = *(const bf16_8*)(ap + colx1);
    }
    asm volatile("s_waitcnt lgkmcnt(0)" ::: "memory");  // all reads in regs
    __builtin_amdgcn_s_barrier();                       // all waves done reading buf g
    asm volatile("" ::: "memory");

    if (g + 2 < nG) STAGE_GRP(g + 2);   // refill current buffer slots

    __builtin_amdgcn_s_setprio(1);
#pragma unroll
    for (int mi = 0; mi < 4; ++mi)
#pragma unroll
      for (int ni = 0; ni < 2; ++ni) {
        acc[0][mi][ni] = mfma16(af0[mi][0], b0[ni][0], acc[0][mi][ni]);
        acc[0][mi][ni] = mfma16(af0[mi][1], b0[ni][1], acc[0][mi][ni]);
      }
#pragma unroll
    for (int mi = 0; mi < 4; ++mi)
#pragma unroll
      for (int ni = 0; ni < 2; ++ni) {
        acc[1][mi][ni] = mfma16(af0[mi][0], b1[ni][0], acc[1][mi][ni]);
        acc[1][mi][ni] = mfma16(af0[mi][1], b1[ni][1], acc[1][mi][ni]);
      }
#pragma unroll
    for (int mi = 0; mi < 4; ++mi)
#pragma unroll
      for (int ni = 0; ni < 2; ++ni) {
        acc[2][mi][ni] = mfma16(af1[mi][0], b0[ni][0], acc[2][mi][ni]);
        acc[2][mi][ni] = mfma16(af1[mi][1], b0[ni][1], acc[2][mi][ni]);
      }
#pragma unroll
    for (int mi = 0; mi < 4; ++mi)
#pragma unroll
      for (int ni = 0; ni < 2; ++ni) {
        acc[3][mi][ni] = mfma16(af1[mi][0], b1[ni][0], acc[3][mi][ni]);
        acc[3][mi][ni] = mfma16(af1[mi][1], b1[ni][1], acc[3][mi][ni]);
      }
    __builtin_amdgcn_s_setprio(0);

    if (g + 2 < nG)      asm volatile("s_waitcnt vmcnt(8)" ::: "memory");
    else if (g + 1 < nG) asm volatile("s_waitcnt vmcnt(0)" ::: "memory");
    __builtin_amdgcn_s_barrier();        // buffer g+1 landed & visible
    asm volatile("" ::: "memory");
  }

  if (wsel < 2) {
    const float qscale = wsel == 0 ? 0.08838834764831845f * 1.4426950408889634f
                                   : 1.0f;
    __bf16* O = wsel == 0 ? Qo : Ko;
#pragma unroll
    for (int q = 0; q < 4; ++q)
#pragma unroll
      for (int mi = 0; mi < 4; ++mi)
#pragma unroll
        for (int ni = 0; ni < 2; ++ni)
#pragma unroll
          for (int r = 0; r < 4; ++r) {
            int row = m0 + (q >> 1) * 128 + wsm64 + mi * 16 + quad * 4 + r;
            int col = nloc + (q & 1) * 128 + wsn32 + ni * 16 + l16;
            float self = acc[q][mi][ni][r];
            float oth = __shfl_xor(self, 1);
            int s = row & (S_ - 1);
            int dh = col & (DH_ - 1);
            float c = fc[s * (DH_ / 2) + (dh >> 1)];
            float sn = fs[s * (DH_ / 2) + (dh >> 1)];
            float o = (dh & 1) ? (oth * sn + self * c) : (self * c - oth * sn);
            O[(size_t)row * 2048 + col] = (__bf16)(o * qscale);
          }
  } else {
    // V: transpose to Vo[b][h][dh][s] via 4 passes of 64 cols through LDS.
    auto Ts = (__bf16(*)[264])smem8;   // [64][264], aliases staging (loop done)
    const int b = m0 >> 11, sb = m0 & (S_ - 1);
#pragma unroll
    for (int p = 0; p < 4; ++p) {
      __syncthreads();
      if ((wsn32 >> 6) == (p & 1)) {   // waves whose cols fall in this pass
        const int qb = p >> 1;
#pragma unroll
        for (int qa = 0; qa < 2; ++qa)
#pragma unroll
          for (int mi = 0; mi < 4; ++mi)
#pragma unroll
            for (int ni = 0; ni < 2; ++ni) {
              int cl = (wsn32 & 32) + ni * 16 + l16;           // local col 0..63
              int rl = qa * 128 + wsm64 + mi * 16 + quad * 4;  // local row
              bf16_4 pk;
#pragma unroll
              for (int r = 0; r < 4; ++r) pk[r] = (__bf16)acc[qa * 2 + qb][mi][ni][r];
              *(bf16_4*)&Ts[cl][rl] = pk;
            }
      }
      __syncthreads();
      const int h = (nloc + p * 64) >> 7, dh0 = (nloc + p * 64) & (DH_ - 1);
      __bf16* vb = Vo + ((size_t)(b * H_ + h) * DH_ + dh0) * S_ + sb;
#pragma unroll
      for (int i = 0; i < 4; ++i) {
        int dhl = i * 16 + (tid >> 5);
        int sc = (tid & 31) * 8;
        *(bf16_8*)(vb + (size_t)dhl * S_ + sc) = *(const bf16_8*)&Ts[dhl][sc];
      }
    }
  }
}

// Fused QKV GEMM fallback (no-workspace path), 128x128, staged f32 weights.
template <bool WB>
__global__ __launch_bounds__(256) void qkv_gemm(
    const __bf16* __restrict__ A,
    const float* __restrict__ wqf, const float* __restrict__ wkf,
    const float* __restrict__ wvf,
    const __bf16* __restrict__ wqb, const __bf16* __restrict__ wkb,
    const __bf16* __restrict__ wvb,
    const float* __restrict__ fc, const float* __restrict__ fs,
    __bf16* __restrict__ Qo, __bf16* __restrict__ Ko, __bf16* __restrict__ Vo)
{
  constexpr int TILE = 128 * 32;
  constexpr int STAGE_ELEMS = WB ? 4 * TILE : (128 * 32 + 128 * 40);
  constexpr int TS_ELEMS = 64 * 136;
  constexpr int SM_ELEMS = STAGE_ELEMS > TS_ELEMS ? STAGE_ELEMS : TS_ELEMS;
  __shared__ __align__(16) __bf16 smem[SM_ELEMS];

  const int tid = threadIdx.x;
  const int wave = tid >> 6, lane = tid & 63;
  const int quad = lane >> 4, l16 = lane & 15;
  const int m0 = blockIdx.y * 128, n0 = blockIdx.x * 128;
  const int wsel = n0 >> 11, nloc = n0 & 2047;
  const int wm = (wave >> 1) * 64, wn = (wave & 1) * 64;
  const __bf16* agl = A + (size_t)(m0 + wave * 32 + (lane >> 2)) * 2048 + (lane & 3) * 8;
  f32x4 acc[4][4] = {};
  if (WB) {
    const __bf16* Wbp = wsel == 0 ? wqb : wsel == 1 ? wkb : wvb;
    const __bf16* wgl = Wbp + (size_t)(nloc + wave * 32 + (lane >> 2)) * 2048 + (lane & 3) * 8;
    auto STAGE = [&](int k0, int p) {
      __bf16* ab = smem + p * TILE + (wave * 32) * 32;
      __bf16* wb2 = smem + 2 * TILE + p * TILE + (wave * 32) * 32;
      async16(agl + k0,             ab);
      async16(agl + 16 * 2048 + k0, ab + 16 * 32);
      async16(wgl + k0,             wb2);
      async16(wgl + 16 * 2048 + k0, wb2 + 16 * 32);
    };
    STAGE(0, 0);
#pragma unroll 2
    for (int it = 0; it < 64; ++it) {
      const int p = it & 1;
      if (it + 1 < 64) {
        STAGE((it + 1) * 32, p ^ 1);
        asm volatile("s_waitcnt vmcnt(4)" ::: "memory");
      } else {
        asm volatile("s_waitcnt vmcnt(0)" ::: "memory");
      }
      __builtin_amdgcn_s_barrier();
      asm volatile("" ::: "memory");
      const __bf16* Ab = smem + p * TILE;
      const __bf16* Wbuf = smem + 2 * TILE + p * TILE;
      bf16_8 af[4], bfr[4];
      for (int i = 0; i < 4; ++i) {
        af[i]  = *(const bf16_8*)(Ab   + (wm + i * 16 + l16) * 32 + quad * 8);
        bfr[i] = *(const bf16_8*)(Wbuf + (wn + i * 16 + l16) * 32 + quad * 8);
      }
      for (int mi = 0; mi < 4; ++mi)
        for (int ni = 0; ni < 4; ++ni)
          acc[mi][ni] = mfma16(af[mi], bfr[ni], acc[mi][ni]);
      asm volatile("s_waitcnt lgkmcnt(0)" ::: "memory");
      __builtin_amdgcn_s_barrier();
      asm volatile("" ::: "memory");
    }
  } else {
    auto As = (__bf16(*)[32])smem;
    auto Ws = (__bf16(*)[40])(smem + 128 * 32);
    const float* W = wsel == 0 ? wqf : wsel == 1 ? wkf : wvf;
    const int srow = tid >> 1, scol = (tid & 1) * 16;
    const float* wg = W + (size_t)(nloc + srow) * 2048 + scol;
    for (int k0 = 0; k0 < 2048; k0 += 32) {
      __syncthreads();
      async16(agl + k0,             &As[wave * 32][0]);
      async16(agl + 16 * 2048 + k0, &As[wave * 32 + 16][0]);
      *(bf16_8*)&Ws[srow][scol]     = load8(wg + k0);
      *(bf16_8*)&Ws[srow][scol + 8] = load8(wg + k0 + 8);
      __syncthreads();
      bf16_8 af[4], bfr[4];
      for (int i = 0; i < 4; ++i) {
        af[i]  = *(const bf16_8*)&As[wm + i * 16 + l16][quad * 8];
        bfr[i] = *(const bf16_8*)&Ws[wn + i * 16 + l16][quad * 8];
      }
      for (int mi = 0; mi < 4; ++mi)
        for (int ni = 0; ni < 4; ++ni)
          acc[mi][ni] = mfma16(af[mi], bfr[ni], acc[mi][ni]);
    }
  }
  if (wsel < 2) {
    const float qscale = wsel == 0 ? 0.08838834764831845f * 1.4426950408889634f
                                   : 1.0f;
    __bf16* O = wsel == 0 ? Qo : Ko;
    for (int mi = 0; mi < 4; ++mi)
      for (int ni = 0; ni < 4; ++ni)
        for (int r = 0; r < 4; ++r) {
          int row = m0 + wm + mi * 16 + quad * 4 + r;
          int col = nloc + wn + ni * 16 + l16;
          float self = acc[mi][ni][r];
          float oth = __shfl_xor(self, 1);
          int s = row & (S_ - 1);
          int dh = col & (DH_ - 1);
          float c = fc[s * (DH_ / 2) + (dh >> 1)];
          float sn = fs[s * (DH_ / 2) + (dh >> 1)];
          float o = (dh & 1) ? (oth * sn + self * c) : (self * c - oth * sn);
          O[(size_t)row * 2048 + col] = (__bf16)(o * qscale);
        }
  } else {
    auto Ts = (__bf16(*)[136])smem;
    const int b = m0 >> 11, h = nloc >> 7;
    __bf16* vb = Vo + ((size_t)(b * H_ + h) * DH_) * S_ + (m0 & (S_ - 1));
    for (int p = 0; p < 2; ++p) {
      __syncthreads();
      if ((wn >> 6) == p) {
        for (int mi = 0; mi < 4; ++mi)
          for (int ni = 0; ni < 4; ++ni) {
            int cl = ni * 16 + l16;
            int rl = wm + mi * 16 + quad * 4;
            bf16_4 pk;
            for (int r = 0; r < 4; ++r) pk[r] = (__bf16)acc[mi][ni][r];
            *(bf16_4*)&Ts[cl][rl] = pk;
          }
      }
      __syncthreads();
      for (int i = 0; i < 4; ++i) {
        int dh = p * 64 + i * 16 + (tid >> 4);
        int sc = (tid & 15) * 8;
        *(bf16_8*)(vb + (size_t)dh * S_ + sc) = *(const bf16_8*)&Ts[dh - p * 64][sc];
      }
    }
  }
}

// Output GEMM: C(f32) = A(bf16) * W^T. Depth-1 pipeline (round-8 verified).
template <bool WB>
__global__ __launch_bounds__(256) void out_gemm(
    const __bf16* __restrict__ A, const float* __restrict__ Wf,
    const __bf16* __restrict__ Wb, float* __restrict__ C)
{
  constexpr int TILE = 128 * 32;
  constexpr int SM_ELEMS = WB ? 4 * TILE : (128 * 32 + 128 * 40);
  __shared__ __align__(16) __bf16 smem[SM_ELEMS];
  const int tid = threadIdx.x;
  const int wave = tid >> 6, lane = tid & 63;
  const int quad = lane >> 4, l16 = lane & 15;
  const int m0 = blockIdx.y * 128, n0 = blockIdx.x * 128;
  const int wm = (wave >> 1) * 64, wn = (wave & 1) * 64;
  const __bf16* agl = A + (size_t)(m0 + wave * 32 + (lane >> 2)) * 2048 + (lane & 3) * 8;
  f32x4 acc[4][4] = {};
  if (WB) {
    const __bf16* wgl = Wb + (size_t)(n0 + wave * 32 + (lane >> 2)) * 2048 + (lane & 3) * 8;
    auto STAGE = [&](int k0, int p) {
      __bf16* ab = smem + p * TILE + (wave * 32) * 32;
      __bf16* wb2 = smem + 2 * TILE + p * TILE + (wave * 32) * 32;
      async16(agl + k0,             ab);
      async16(agl + 16 * 2048 + k0, ab + 16 * 32);
      async16(wgl + k0,             wb2);
      async16(wgl + 16 * 2048 + k0, wb2 + 16 * 32);
    };
    STAGE(0, 0);
#pragma unroll 2
    for (int it = 0; it < 64; ++it) {
      const int p = it & 1;
      if (it + 1 < 64) {
        STAGE((it + 1) * 32, p ^ 1);
        asm volatile("s_waitcnt vmcnt(4)" ::: "memory");
      } else {
        asm volatile("s_waitcnt vmcnt(0)" ::: "memory");
      }
      __builtin_amdgcn_s_barrier();
      asm volatile("" ::: "memory");
      const __bf16* Ab = smem + p * TILE;
      const __bf16* Wbuf = smem + 2 * TILE + p * TILE;
      bf16_8 af[4], bfr[4];
      for (int i = 0; i < 4; ++i) {
        af[i]  = *(const bf16_8*)(Ab   + (wm + i * 16 + l16) * 32 + quad * 8);
        bfr[i] = *(const bf16_8*)(Wbuf + (wn + i * 16 + l16) * 32 + quad * 8);
      }
      for (int mi = 0; mi < 4; ++mi)
        for (int ni = 0; ni < 4; ++ni)
          acc[mi][ni] = mfma16(af[mi], bfr[ni], acc[mi][ni]);
      asm volatile("s_waitcnt lgkmcnt(0)" ::: "memory");
      __builtin_amdgcn_s_barrier();
      asm volatile("" ::: "memory");
    }
  } else {
    auto As = (__bf16(*)[32])smem;
    auto Ws = (__bf16(*)[40])(smem + 128 * 32);
    const int srow = tid >> 1, scol = (tid & 1) * 16;
    const float* wg = Wf + (size_t)(n0 + srow) * 2048 + scol;
    for (int k0 = 0; k0 < 2048; k0 += 32) {
      __syncthreads();
      async16(agl + k0,             &As[wave * 32][0]);
      async16(agl + 16 * 2048 + k0, &As[wave * 32 + 16][0]);
      *(bf16_8*)&Ws[srow][scol]     = load8(wg + k0);
      *(bf16_8*)&Ws[srow][scol + 8] = load8(wg + k0 + 8);
      __syncthreads();
      bf16_8 af[4], bfr[4];
      for (int i = 0; i < 4; ++i) {
        af[i]  = *(const bf16_8*)&As[wm + i * 16 + l16][quad * 8];
        bfr[i] = *(const bf16_8*)&Ws[wn + i * 16 + l16][quad * 8];
      }
      for (int mi = 0; mi < 4; ++mi)
        for (int ni = 0; ni < 4; ++ni)
          acc[mi][ni] = mfma16(af[mi], bfr[ni], acc[mi][ni]);
    }
  }
  for (int mi = 0; mi < 4; ++mi)
    for (int ni = 0; ni < 4; ++ni)
      for (int r = 0; r < 4; ++r) {
        int row = m0 + wm + mi * 16 + quad * 4 + r;
        int col = n0 + wn + ni * 16 + l16;
        C[(size_t)row * 2048 + col] = acc[mi][ni][r];
      }
}

// Flash attention v3 (round-3 verified) + XCD swizzle (round-8 verified).
__global__ __launch_bounds__(256) void attn_kernel(
    const __bf16* __restrict__ Q, const __bf16* __restrict__ K,
    const __bf16* __restrict__ Vt_g, __bf16* __restrict__ O)
{
  __shared__ __bf16 Ks[2][64 * 128];
  __shared__ __bf16 Vt[128 * 64];
  __shared__ __bf16 Ps[4][32][72];
  const int tid = threadIdx.x;
  const int wave = tid >> 6, lane = tid & 63;
  const int quad = lane >> 4, l16 = lane & 15;
  const int fid = blockIdx.y * gridDim.x + blockIdx.x;
  const int tid_swz = (fid & 7) * 64 + (fid >> 3);
  const int bh = tid_swz >> 4;
  const int qt = 15 - (tid_swz & 15);
  const size_t base = (size_t)(bh >> 4) * S_ * D_ + (size_t)(bh & 15) * DH_;
  const size_t vtb = (size_t)bh * DH_ * S_;
  const int q0 = qt * 128;
  const int wmin = q0 + wave * 32;

  bf16_8 qf[2][4];
  for (int qs = 0; qs < 2; ++qs) {
    int qrow = wmin + qs * 16 + l16;
    for (int kk = 0; kk < 4; ++kk)
      qf[qs][kk] = *(const bf16_8*)(Q + base + (size_t)qrow * D_ + kk * 32 + quad * 8);
  }
  asm volatile("s_waitcnt vmcnt(0)" ::: "memory");

  const int krs = wave * 4 + (lane >> 4);
  const __bf16* kgl = K + base + (size_t)krs * D_ + ((lane & 15) ^ krs) * 8;
  const int vrs = wave * 8 + (lane >> 3);
  const __bf16* vgl = Vt_g + vtb + (size_t)vrs * S_ + ((lane & 7) ^ (lane >> 3)) * 8;

  f32x4 oacc[2][8] = {};
  float lsum[2][4] = {};
  const int nt = 2 * qt + 2;

  for (int p = 0; p < 4; ++p)
    async16(kgl + (size_t)(p * 16) * D_, Ks[0] + (p * 16 + wave * 4) * 128);
  for (int p = 0; p < 4; ++p)
    async16(vgl + (size_t)(p * 32) * S_, Vt + (p * 32 + wave * 8) * 64);

  int cur = 0;
  for (int kt = 0; kt < nt; ++kt) {
    const bool more = (kt + 1 < nt);
    if (more) {
      for (int p = 0; p < 4; ++p)
        async16(kgl + (size_t)((kt + 1) * 64 + p * 16) * D_,
                Ks[cur ^ 1] + (p * 16 + wave * 4) * 128);
      asm volatile("s_waitcnt vmcnt(8)" ::: "memory");
    } else {
      asm volatile("s_waitcnt vmcnt(4)" ::: "memory");
    }
    __builtin_amdgcn_s_barrier();
    asm volatile("" ::: "memory");

    const bool active = (kt * 64 <= wmin + 31);
    if (active) {
      const bool diag = (kt * 64 + 63 > wmin);
      const __bf16* ksb = Ks[cur];
      for (int n = 0; n < 4; ++n) {
        f32x4 s0 = {}, s1 = {};
        __builtin_amdgcn_s_setprio(1);
#pragma unroll
        for (int kk = 0; kk < 4; ++kk) {
          bf16_8 kf = *(const bf16_8*)&ksb[(n * 16 + l16) * 128 + (((kk * 4 + quad) ^ l16) * 8)];
          s0 = mfma16(qf[0][kk], kf, s0);
          s1 = mfma16(qf[1][kk], kf, s1);
        }
        __builtin_amdgcn_s_setprio(0);
#pragma unroll
        for (int qs = 0; qs < 2; ++qs) {
          f32x4 sv = qs ? s1 : s0;
          for (int r = 0; r < 4; ++r) {
            float v = sv[r];
            if (diag) {
              int qr = wmin + qs * 16 + quad * 4 + r;
              if (kt * 64 + n * 16 + l16 > qr) v = -INFINITY;
            }
            float p = exp2f(v);
            lsum[qs][r] += p;
            Ps[wave][qs * 16 + quad * 4 + r][n * 16 + l16] = (__bf16)p;
          }
        }
      }
    }

    if (more) asm volatile("s_waitcnt vmcnt(4)" ::: "memory");
    else      asm volatile("s_waitcnt vmcnt(0)" ::: "memory");
    __builtin_amdgcn_s_barrier();
    asm volatile("" ::: "memory");

    if (active) {
      bf16_8 pf0[2], pf1[2];
      for (int qs = 0; qs < 2; ++qs) {
        pf0[qs] = *(const bf16_8*)&Ps[wave][qs * 16 + l16][quad * 8];
        pf1[qs] = *(const bf16_8*)&Ps[wave][qs * 16 + l16][32 + quad * 8];
      }
      __builtin_amdgcn_s_setprio(1);
#pragma unroll
      for (int nc = 0; nc < 8; ++nc) {
        bf16_8 vf0 = *(const bf16_8*)&Vt[(nc * 16 + l16) * 64 + ((quad ^ (l16 & 7)) * 8)];
        bf16_8 vf1 = *(const bf16_8*)&Vt[(nc * 16 + l16) * 64 + (((quad + 4) ^ (l16 & 7)) * 8)];
        oacc[0][nc] = mfma16(pf0[0], vf0, oacc[0][nc]);
        oacc[0][nc] = mfma16(pf1[0], vf1, oacc[0][nc]);
        oacc[1][nc] = mfma16(pf0[1], vf0, oacc[1][nc]);
        oacc[1][nc] = mfma16(pf1[1], vf1, oacc[1][nc]);
      }
      __builtin_amdgcn_s_setprio(0);
    }

    asm volatile("s_waitcnt lgkmcnt(0)" ::: "memory");
    __builtin_amdgcn_s_barrier();
    asm volatile("" ::: "memory");
    if (more)
      for (int p = 0; p < 4; ++p)
        async16(vgl + (size_t)(p * 32) * S_ + (size_t)(kt + 1) * 64,
                Vt + (p * 32 + wave * 8) * 64);
    cur ^= 1;
  }

  for (int qs = 0; qs < 2; ++qs)
    for (int r = 0; r < 4; ++r) {
      float l = lsum[qs][r];
      l += __shfl_xor(l, 1);
      l += __shfl_xor(l, 2);
      l += __shfl_xor(l, 4);
      l += __shfl_xor(l, 8);
      float rinv = 1.f / l;
      int qr = wmin + qs * 16 + quad * 4 + r;
      for (int nc = 0; nc < 8; ++nc)
        O[base + (size_t)qr * D_ + nc * 16 + l16] = (__bf16)(oacc[qs][nc][r] * rinv);
    }
}

extern "C" void kernel_launch(void* const* d_in, const int* in_sizes, int n_in,
                              void* d_out, int out_size, void* d_ws, size_t ws_size,
                              hipStream_t stream)
{
  const float* x    = (const float*)d_in[0];
  const float* fcos = (const float*)d_in[1];
  const float* fsin = (const float*)d_in[2];
  // d_in[3] = causal mask: implied by kernel structure, unused
  const float* wq   = (const float*)d_in[4];
  const float* wk   = (const float*)d_in[5];
  const float* wv   = (const float*)d_in[6];
  const float* wo   = (const float*)d_in[7];
  float* out = (float*)d_out;

  const size_t T = (size_t)B_ * S_ * D_;   // 8.39M elems
  const size_t W = (size_t)D_ * D_;        // 4.19M elems
  __bf16* xb  = (__bf16*)d_ws;  // x bf16; reused as attention-out
  __bf16* qw  = xb + T;
  __bf16* kw  = qw + T;
  __bf16* vt  = kw + T;
  __bf16* wqb = vt + T;
  __bf16* wkb = wqb + W;
  __bf16* wvb = wkb + W;
  __bf16* wob = wvb + W;
  __bf16* ow  = xb;

  const bool wb = ws_size >= (4 * T + 4 * W) * sizeof(__bf16);  // 100.7 MB
  const int W8 = (int)(W / 8);
  cvt_all<<<(wb ? 6 : 2) * W8 / 256, 256, 0, stream>>>(
      x, wq, wk, wv, wo, xb, wqb, wkb, wvb, wob);
  if (wb)
    qkv_gemm8<<<dim3(24, 16), 512, 0, stream>>>(
        xb, wqb, wkb, wvb, fcos, fsin, qw, kw, vt);
  else
    qkv_gemm<false><<<dim3(48, 32), 256, 0, stream>>>(
        xb, wq, wk, wv, nullptr, nullptr, nullptr, fcos, fsin, qw, kw, vt);
  attn_kernel<<<dim3(S_ / 128, B_ * H_), 256, 0, stream>>>(qw, kw, vt, ow);
  if (wb)
    out_gemm<true><<<dim3(16, 32), 256, 0, stream>>>(ow, nullptr, wob, out);
  else
    out_gemm<false><<<dim3(16, 32), 256, 0, stream>>>(ow, wo, nullptr, out);
}

// Round 16
// 410.994 us; speedup vs baseline: 1.0209x; 1.0209x over previous
//
#include <hip/hip_runtime.h>

#define B_ 2
#define S_ 2048
#define D_ 2048
#define H_ 16
#define DH_ 128

typedef __bf16 bf16_8 __attribute__((ext_vector_type(8)));
typedef __bf16 bf16_4 __attribute__((ext_vector_type(4)));
typedef float f32x4 __attribute__((ext_vector_type(4)));

__device__ __forceinline__ f32x4 mfma16(bf16_8 a, bf16_8 b, f32x4 c) {
  return __builtin_amdgcn_mfma_f32_16x16x32_bf16(a, b, c, 0, 0, 0);
}

__device__ __forceinline__ bf16_8 load8(const float* p) {
  f32x4 a = *(const f32x4*)p;
  f32x4 b = *(const f32x4*)(p + 4);
  bf16_8 r;
  r[0] = (__bf16)a[0]; r[1] = (__bf16)a[1]; r[2] = (__bf16)a[2]; r[3] = (__bf16)a[3];
  r[4] = (__bf16)b[0]; r[5] = (__bf16)b[1]; r[6] = (__bf16)b[2]; r[7] = (__bf16)b[3];
  return r;
}

// async global->LDS, 16B/lane, wave-uniform LDS base (HW adds lane*16)
__device__ __forceinline__ void async16(const __bf16* g, __bf16* l) {
  __builtin_amdgcn_global_load_lds(
      (const __attribute__((address_space(1))) void*)g,
      (__attribute__((address_space(3))) void*)l, 16, 0, 0);
}

// f32->bf16 convert: x (2 chunks) + 4 weights (1 chunk each).
__global__ __launch_bounds__(256) void cvt_all(
    const float* __restrict__ x, const float* __restrict__ wq,
    const float* __restrict__ wk, const float* __restrict__ wv,
    const float* __restrict__ wo, __bf16* __restrict__ xb,
    __bf16* __restrict__ wqb, __bf16* __restrict__ wkb,
    __bf16* __restrict__ wvb, __bf16* __restrict__ wob)
{
  const int W8 = (D_ * D_) / 8;   // 2^19
  int i = blockIdx.x * 256 + threadIdx.x;
  if (i < 2 * W8) {
    *(bf16_8*)(xb + (size_t)i * 8) = load8(x + (size_t)i * 8);
  } else {
    int j = i - 2 * W8;
    int sel = j >> 19, off = j & (W8 - 1);
    const float* s = sel == 0 ? wq : sel == 1 ? wk : sel == 2 ? wv : wo;
    __bf16* d = sel == 0 ? wqb : sel == 1 ? wkb : sel == 2 ? wvb : wob;
    *(bf16_8*)(d + (size_t)off * 8) = load8(s + (size_t)off * 8);
  }
}

// ============================================================================
// qkv_gemm8: 256x128 pipelined GEMM, 512 threads, BK=64 double-buffered.
// Round-16: BM=256 BN=128 -> grid 48x16 = 768 blocks = EXACTLY 3/CU
// (round-14's 256x256 grid of 384 at 1 block/CU had a 25% idle tail:
// 128 CUs ran 2 sequential blocks, 128 ran 1; measured MfmaUtil 32% =
// ~42% inner-loop util x 0.75 balance). acc drops to 64 VGPR (150 total),
// LDS = A dbuf 2x32KB + B dbuf 2x16KB = 96 KB.
// Waves: 4M x 2N, per-wave 64x64 slice; per K-tile(64): 16 ds_read_b128,
// 32 MFMA. Schedule = round-15's (refcheck-verified) 2-barrier group:
//   reads(16) -> lgkmcnt(0) -> BARRIER -> stage(g+2) (6 calls)
//   -> 32 MFMA (setprio) -> vmcnt(6) -> BARRIER
// Ledger: prologue grp0+grp1 = 12 loads -> vmcnt(6) = grp0 landed.
// Steady: outstanding = grp(g+1)6 + grp(g+2)6 = 12 -> vmcnt(6) = grp(g+1)
// landed. Tail: g=30 -> vmcnt(0); g=31 -> none.
// Hazard: stage(g+2) overwrites buffer (g&1) whose reads all completed
// before the preceding barrier (MFMA reads registers only). Safe.
// Swizzle: identical 8-chunk/64-elem-row XOR pattern as rounds 12-15.
// ============================================================================
__global__ __launch_bounds__(512, 2) void qkv_gemm8(
    const __bf16* __restrict__ A,
    const __bf16* __restrict__ wqb, const __bf16* __restrict__ wkb,
    const __bf16* __restrict__ wvb,
    const float* __restrict__ fc, const float* __restrict__ fs,
    __bf16* __restrict__ Qo, __bf16* __restrict__ Ko, __bf16* __restrict__ Vo)
{
  __shared__ __align__(16) __bf16 smem8[49152];   // 96 KB
  const int tid = threadIdx.x;
  const int wave = tid >> 6, lane = tid & 63;
  const int quad = lane >> 4, l16 = lane & 15;
  const int wave_m = wave >> 1;          // 0..3 -> 64-row slice
  const int wave_n = wave & 1;           // 0..1 -> 64-col slice
  const int m0 = blockIdx.y * 256, n0 = blockIdx.x * 128;
  const int wsel = n0 >> 11, nloc = n0 & 2047;
  const __bf16* Wb = wsel == 0 ? wqb : wsel == 1 ? wkb : wvb;

  // staging: lane covers row tid>>3 (of 64-row region), swizzled chunk (tid&7)^((tid>>3)&7)
  const int srow = tid >> 3;                       // 0..63
  const int scol = ((tid & 7) ^ ((tid >> 3) & 7)) * 8;
  const __bf16* agl = A  + (size_t)(m0 + srow) * 2048 + scol;
  const __bf16* wgl = Wb + (size_t)(nloc + srow) * 2048 + scol;
  const int ldso = wave * 512;   // wave covers rows wave*8..+8 of each 64-row region

  const int colx0 = (quad * 8) ^ ((l16 & 7) * 8);
  const int colx1 = colx0 ^ 32;

  f32x4 acc[4][4] = {};

  // LDS: A at 0 (2 x 16384 elems), B at 32768 (2 x 4096... 2 x 8192 elems)
  auto SA = [&](int kt, int q) {   // q = 0..3, 64 rows each
    async16(agl + (size_t)(q * 64) * 2048 + (size_t)kt * 64,
            smem8 + (kt & 1) * 16384 + q * 4096 + ldso);
  };
  auto SB = [&](int kt, int q) {   // q = 0..1
    async16(wgl + (size_t)(q * 64) * 2048 + (size_t)kt * 64,
            smem8 + 32768 + (kt & 1) * 8192 + q * 4096 + ldso);
  };
  auto STAGE_GRP = [&](int kt) {   // 6 loads
    SA(kt, 0); SA(kt, 1); SA(kt, 2); SA(kt, 3);
    SB(kt, 0); SB(kt, 1);
  };

  STAGE_GRP(0);
  STAGE_GRP(1);
  asm volatile("s_waitcnt vmcnt(6)" ::: "memory");   // group 0 landed
  __builtin_amdgcn_s_barrier();
  asm volatile("" ::: "memory");

  const int nG = 2048 / 64;   // 32
  for (int g = 0; g < nG; ++g) {
    const __bf16* Ab = smem8 + (g & 1) * 16384;
    const __bf16* Bb = smem8 + 32768 + (g & 1) * 8192;
    bf16_8 af[4][2], bf[4][2];

#pragma unroll
    for (int mi = 0; mi < 4; ++mi) {
      const __bf16* ap = Ab + (wave_m * 64 + mi * 16 + l16) * 64;
      af[mi][0] = *(const bf16_8*)(ap + colx0);
      af[mi][1] = *(const bf16_8*)(ap + colx1);
    }
#pragma unroll
    for (int ni = 0; ni < 4; ++ni) {
      const __bf16* bp = Bb + (wave_n * 64 + ni * 16 + l16) * 64;
      bf[ni][0] = *(const bf16_8*)(bp + colx0);
      bf[ni][1] = *(const bf16_8*)(bp + colx1);
    }
    asm volatile("s_waitcnt lgkmcnt(0)" ::: "memory");  // all reads in regs
    __builtin_amdgcn_s_barrier();                       // all waves done w/ buf g
    asm volatile("" ::: "memory");

    if (g + 2 < nG) STAGE_GRP(g + 2);   // refill just-read buffer

    __builtin_amdgcn_s_setprio(1);
#pragma unroll
    for (int mi = 0; mi < 4; ++mi)
#pragma unroll
      for (int ni = 0; ni < 4; ++ni) {
        acc[mi][ni] = mfma16(af[mi][0], bf[ni][0], acc[mi][ni]);
        acc[mi][ni] = mfma16(af[mi][1], bf[ni][1], acc[mi][ni]);
      }
    __builtin_amdgcn_s_setprio(0);

    if (g + 2 < nG)      asm volatile("s_waitcnt vmcnt(6)" ::: "memory");
    else if (g + 1 < nG) asm volatile("s_waitcnt vmcnt(0)" ::: "memory");
    __builtin_amdgcn_s_barrier();        // buffer g+1 landed & visible
    asm volatile("" ::: "memory");
  }

  if (wsel < 2) {
    const float qscale = wsel == 0 ? 0.08838834764831845f * 1.4426950408889634f
                                   : 1.0f;
    __bf16* O = wsel == 0 ? Qo : Ko;
#pragma unroll
    for (int mi = 0; mi < 4; ++mi)
#pragma unroll
      for (int ni = 0; ni < 4; ++ni)
#pragma unroll
        for (int r = 0; r < 4; ++r) {
          int row = m0 + wave_m * 64 + mi * 16 + quad * 4 + r;
          int col = nloc + wave_n * 64 + ni * 16 + l16;
          float self = acc[mi][ni][r];
          float oth = __shfl_xor(self, 1);
          int s = row & (S_ - 1);
          int dh = col & (DH_ - 1);
          float c = fc[s * (DH_ / 2) + (dh >> 1)];
          float sn = fs[s * (DH_ / 2) + (dh >> 1)];
          float o = (dh & 1) ? (oth * sn + self * c) : (self * c - oth * sn);
          O[(size_t)row * 2048 + col] = (__bf16)(o * qscale);
        }
  } else {
    // V: transpose 256(s) x 128(dh) tile to Vo[b][h][dh][s], 2 passes of 64 dh.
    auto Ts = (__bf16(*)[264])smem8;   // [64][264], aliases staging (loop done)
    const int b = m0 >> 11, sb = m0 & (S_ - 1);
    const int h = nloc >> 7;
#pragma unroll
    for (int p = 0; p < 2; ++p) {
      __syncthreads();
      if (wave_n == p) {
#pragma unroll
        for (int mi = 0; mi < 4; ++mi)
#pragma unroll
          for (int ni = 0; ni < 4; ++ni) {
            int cl = ni * 16 + l16;                    // dh within pass, 0..63
            int rl = wave_m * 64 + mi * 16 + quad * 4; // s within tile, 0..255
            bf16_4 pk;
#pragma unroll
            for (int r = 0; r < 4; ++r) pk[r] = (__bf16)acc[mi][ni][r];
            *(bf16_4*)&Ts[cl][rl] = pk;
          }
      }
      __syncthreads();
      __bf16* vb = Vo + ((size_t)(b * H_ + h) * DH_ + p * 64) * S_ + sb;
#pragma unroll
      for (int i = 0; i < 4; ++i) {
        int dhl = i * 16 + (tid >> 5);
        int sc = (tid & 31) * 8;
        *(bf16_8*)(vb + (size_t)dhl * S_ + sc) = *(const bf16_8*)&Ts[dhl][sc];
      }
    }
  }
}

// Fused QKV GEMM fallback (no-workspace path), 128x128, staged f32 weights.
template <bool WB>
__global__ __launch_bounds__(256) void qkv_gemm(
    const __bf16* __restrict__ A,
    const float* __restrict__ wqf, const float* __restrict__ wkf,
    const float* __restrict__ wvf,
    const __bf16* __restrict__ wqb, const __bf16* __restrict__ wkb,
    const __bf16* __restrict__ wvb,
    const float* __restrict__ fc, const float* __restrict__ fs,
    __bf16* __restrict__ Qo, __bf16* __restrict__ Ko, __bf16* __restrict__ Vo)
{
  constexpr int TILE = 128 * 32;
  constexpr int STAGE_ELEMS = WB ? 4 * TILE : (128 * 32 + 128 * 40);
  constexpr int TS_ELEMS = 64 * 136;
  constexpr int SM_ELEMS = STAGE_ELEMS > TS_ELEMS ? STAGE_ELEMS : TS_ELEMS;
  __shared__ __align__(16) __bf16 smem[SM_ELEMS];

  const int tid = threadIdx.x;
  const int wave = tid >> 6, lane = tid & 63;
  const int quad = lane >> 4, l16 = lane & 15;
  const int m0 = blockIdx.y * 128, n0 = blockIdx.x * 128;
  const int wsel = n0 >> 11, nloc = n0 & 2047;
  const int wm = (wave >> 1) * 64, wn = (wave & 1) * 64;
  const __bf16* agl = A + (size_t)(m0 + wave * 32 + (lane >> 2)) * 2048 + (lane & 3) * 8;
  f32x4 acc[4][4] = {};
  if (WB) {
    const __bf16* Wbp = wsel == 0 ? wqb : wsel == 1 ? wkb : wvb;
    const __bf16* wgl = Wbp + (size_t)(nloc + wave * 32 + (lane >> 2)) * 2048 + (lane & 3) * 8;
    auto STAGE = [&](int k0, int p) {
      __bf16* ab = smem + p * TILE + (wave * 32) * 32;
      __bf16* wb2 = smem + 2 * TILE + p * TILE + (wave * 32) * 32;
      async16(agl + k0,             ab);
      async16(agl + 16 * 2048 + k0, ab + 16 * 32);
      async16(wgl + k0,             wb2);
      async16(wgl + 16 * 2048 + k0, wb2 + 16 * 32);
    };
    STAGE(0, 0);
#pragma unroll 2
    for (int it = 0; it < 64; ++it) {
      const int p = it & 1;
      if (it + 1 < 64) {
        STAGE((it + 1) * 32, p ^ 1);
        asm volatile("s_waitcnt vmcnt(4)" ::: "memory");
      } else {
        asm volatile("s_waitcnt vmcnt(0)" ::: "memory");
      }
      __builtin_amdgcn_s_barrier();
      asm volatile("" ::: "memory");
      const __bf16* Ab = smem + p * TILE;
      const __bf16* Wbuf = smem + 2 * TILE + p * TILE;
      bf16_8 af[4], bfr[4];
      for (int i = 0; i < 4; ++i) {
        af[i]  = *(const bf16_8*)(Ab   + (wm + i * 16 + l16) * 32 + quad * 8);
        bfr[i] = *(const bf16_8*)(Wbuf + (wn + i * 16 + l16) * 32 + quad * 8);
      }
      for (int mi = 0; mi < 4; ++mi)
        for (int ni = 0; ni < 4; ++ni)
          acc[mi][ni] = mfma16(af[mi], bfr[ni], acc[mi][ni]);
      asm volatile("s_waitcnt lgkmcnt(0)" ::: "memory");
      __builtin_amdgcn_s_barrier();
      asm volatile("" ::: "memory");
    }
  } else {
    auto As = (__bf16(*)[32])smem;
    auto Ws = (__bf16(*)[40])(smem + 128 * 32);
    const float* W = wsel == 0 ? wqf : wsel == 1 ? wkf : wvf;
    const int srow = tid >> 1, scol = (tid & 1) * 16;
    const float* wg = W + (size_t)(nloc + srow) * 2048 + scol;
    for (int k0 = 0; k0 < 2048; k0 += 32) {
      __syncthreads();
      async16(agl + k0,             &As[wave * 32][0]);
      async16(agl + 16 * 2048 + k0, &As[wave * 32 + 16][0]);
      *(bf16_8*)&Ws[srow][scol]     = load8(wg + k0);
      *(bf16_8*)&Ws[srow][scol + 8] = load8(wg + k0 + 8);
      __syncthreads();
      bf16_8 af[4], bfr[4];
      for (int i = 0; i < 4; ++i) {
        af[i]  = *(const bf16_8*)&As[wm + i * 16 + l16][quad * 8];
        bfr[i] = *(const bf16_8*)&Ws[wn + i * 16 + l16][quad * 8];
      }
      for (int mi = 0; mi < 4; ++mi)
        for (int ni = 0; ni < 4; ++ni)
          acc[mi][ni] = mfma16(af[mi], bfr[ni], acc[mi][ni]);
    }
  }
  if (wsel < 2) {
    const float qscale = wsel == 0 ? 0.08838834764831845f * 1.4426950408889634f
                                   : 1.0f;
    __bf16* O = wsel == 0 ? Qo : Ko;
    for (int mi = 0; mi < 4; ++mi)
      for (int ni = 0; ni < 4; ++ni)
        for (int r = 0; r < 4; ++r) {
          int row = m0 + wm + mi * 16 + quad * 4 + r;
          int col = nloc + wn + ni * 16 + l16;
          float self = acc[mi][ni][r];
          float oth = __shfl_xor(self, 1);
          int s = row & (S_ - 1);
          int dh = col & (DH_ - 1);
          float c = fc[s * (DH_ / 2) + (dh >> 1)];
          float sn = fs[s * (DH_ / 2) + (dh >> 1)];
          float o = (dh & 1) ? (oth * sn + self * c) : (self * c - oth * sn);
          O[(size_t)row * 2048 + col] = (__bf16)(o * qscale);
        }
  } else {
    auto Ts = (__bf16(*)[136])smem;
    const int b = m0 >> 11, h = nloc >> 7;
    __bf16* vb = Vo + ((size_t)(b * H_ + h) * DH_) * S_ + (m0 & (S_ - 1));
    for (int p = 0; p < 2; ++p) {
      __syncthreads();
      if ((wn >> 6) == p) {
        for (int mi = 0; mi < 4; ++mi)
          for (int ni = 0; ni < 4; ++ni) {
            int cl = ni * 16 + l16;
            int rl = wm + mi * 16 + quad * 4;
            bf16_4 pk;
            for (int r = 0; r < 4; ++r) pk[r] = (__bf16)acc[mi][ni][r];
            *(bf16_4*)&Ts[cl][rl] = pk;
          }
      }
      __syncthreads();
      for (int i = 0; i < 4; ++i) {
        int dh = p * 64 + i * 16 + (tid >> 4);
        int sc = (tid & 15) * 8;
        *(bf16_8*)(vb + (size_t)dh * S_ + sc) = *(const bf16_8*)&Ts[dh - p * 64][sc];
      }
    }
  }
}

// Output GEMM: C(f32) = A(bf16) * W^T. Depth-1 pipeline (round-8 verified).
template <bool WB>
__global__ __launch_bounds__(256) void out_gemm(
    const __bf16* __restrict__ A, const float* __restrict__ Wf,
    const __bf16* __restrict__ Wb, float* __restrict__ C)
{
  constexpr int TILE = 128 * 32;
  constexpr int SM_ELEMS = WB ? 4 * TILE : (128 * 32 + 128 * 40);
  __shared__ __align__(16) __bf16 smem[SM_ELEMS];
  const int tid = threadIdx.x;
  const int wave = tid >> 6, lane = tid & 63;
  const int quad = lane >> 4, l16 = lane & 15;
  const int m0 = blockIdx.y * 128, n0 = blockIdx.x * 128;
  const int wm = (wave >> 1) * 64, wn = (wave & 1) * 64;
  const __bf16* agl = A + (size_t)(m0 + wave * 32 + (lane >> 2)) * 2048 + (lane & 3) * 8;
  f32x4 acc[4][4] = {};
  if (WB) {
    const __bf16* wgl = Wb + (size_t)(n0 + wave * 32 + (lane >> 2)) * 2048 + (lane & 3) * 8;
    auto STAGE = [&](int k0, int p) {
      __bf16* ab = smem + p * TILE + (wave * 32) * 32;
      __bf16* wb2 = smem + 2 * TILE + p * TILE + (wave * 32) * 32;
      async16(agl + k0,             ab);
      async16(agl + 16 * 2048 + k0, ab + 16 * 32);
      async16(wgl + k0,             wb2);
      async16(wgl + 16 * 2048 + k0, wb2 + 16 * 32);
    };
    STAGE(0, 0);
#pragma unroll 2
    for (int it = 0; it < 64; ++it) {
      const int p = it & 1;
      if (it + 1 < 64) {
        STAGE((it + 1) * 32, p ^ 1);
        asm volatile("s_waitcnt vmcnt(4)" ::: "memory");
      } else {
        asm volatile("s_waitcnt vmcnt(0)" ::: "memory");
      }
      __builtin_amdgcn_s_barrier();
      asm volatile("" ::: "memory");
      const __bf16* Ab = smem + p * TILE;
      const __bf16* Wbuf = smem + 2 * TILE + p * TILE;
      bf16_8 af[4], bfr[4];
      for (int i = 0; i < 4; ++i) {
        af[i]  = *(const bf16_8*)(Ab   + (wm + i * 16 + l16) * 32 + quad * 8);
        bfr[i] = *(const bf16_8*)(Wbuf + (wn + i * 16 + l16) * 32 + quad * 8);
      }
      for (int mi = 0; mi < 4; ++mi)
        for (int ni = 0; ni < 4; ++ni)
          acc[mi][ni] = mfma16(af[mi], bfr[ni], acc[mi][ni]);
      asm volatile("s_waitcnt lgkmcnt(0)" ::: "memory");
      __builtin_amdgcn_s_barrier();
      asm volatile("" ::: "memory");
    }
  } else {
    auto As = (__bf16(*)[32])smem;
    auto Ws = (__bf16(*)[40])(smem + 128 * 32);
    const int srow = tid >> 1, scol = (tid & 1) * 16;
    const float* wg = Wf + (size_t)(n0 + srow) * 2048 + scol;
    for (int k0 = 0; k0 < 2048; k0 += 32) {
      __syncthreads();
      async16(agl + k0,             &As[wave * 32][0]);
      async16(agl + 16 * 2048 + k0, &As[wave * 32 + 16][0]);
      *(bf16_8*)&Ws[srow][scol]     = load8(wg + k0);
      *(bf16_8*)&Ws[srow][scol + 8] = load8(wg + k0 + 8);
      __syncthreads();
      bf16_8 af[4], bfr[4];
      for (int i = 0; i < 4; ++i) {
        af[i]  = *(const bf16_8*)&As[wm + i * 16 + l16][quad * 8];
        bfr[i] = *(const bf16_8*)&Ws[wn + i * 16 + l16][quad * 8];
      }
      for (int mi = 0; mi < 4; ++mi)
        for (int ni = 0; ni < 4; ++ni)
          acc[mi][ni] = mfma16(af[mi], bfr[ni], acc[mi][ni]);
    }
  }
  for (int mi = 0; mi < 4; ++mi)
    for (int ni = 0; ni < 4; ++ni)
      for (int r = 0; r < 4; ++r) {
        int row = m0 + wm + mi * 16 + quad * 4 + r;
        int col = n0 + wn + ni * 16 + l16;
        C[(size_t)row * 2048 + col] = acc[mi][ni][r];
      }
}

// Flash attention v3 (round-3 verified) + XCD swizzle (round-8 verified).
__global__ __launch_bounds__(256) void attn_kernel(
    const __bf16* __restrict__ Q, const __bf16* __restrict__ K,
    const __bf16* __restrict__ Vt_g, __bf16* __restrict__ O)
{
  __shared__ __bf16 Ks[2][64 * 128];
  __shared__ __bf16 Vt[128 * 64];
  __shared__ __bf16 Ps[4][32][72];
  const int tid = threadIdx.x;
  const int wave = tid >> 6, lane = tid & 63;
  const int quad = lane >> 4, l16 = lane & 15;
  const int fid = blockIdx.y * gridDim.x + blockIdx.x;
  const int tid_swz = (fid & 7) * 64 + (fid >> 3);
  const int bh = tid_swz >> 4;
  const int qt = 15 - (tid_swz & 15);
  const size_t base = (size_t)(bh >> 4) * S_ * D_ + (size_t)(bh & 15) * DH_;
  const size_t vtb = (size_t)bh * DH_ * S_;
  const int q0 = qt * 128;
  const int wmin = q0 + wave * 32;

  bf16_8 qf[2][4];
  for (int qs = 0; qs < 2; ++qs) {
    int qrow = wmin + qs * 16 + l16;
    for (int kk = 0; kk < 4; ++kk)
      qf[qs][kk] = *(const bf16_8*)(Q + base + (size_t)qrow * D_ + kk * 32 + quad * 8);
  }
  asm volatile("s_waitcnt vmcnt(0)" ::: "memory");

  const int krs = wave * 4 + (lane >> 4);
  const __bf16* kgl = K + base + (size_t)krs * D_ + ((lane & 15) ^ krs) * 8;
  const int vrs = wave * 8 + (lane >> 3);
  const __bf16* vgl = Vt_g + vtb + (size_t)vrs * S_ + ((lane & 7) ^ (lane >> 3)) * 8;

  f32x4 oacc[2][8] = {};
  float lsum[2][4] = {};
  const int nt = 2 * qt + 2;

  for (int p = 0; p < 4; ++p)
    async16(kgl + (size_t)(p * 16) * D_, Ks[0] + (p * 16 + wave * 4) * 128);
  for (int p = 0; p < 4; ++p)
    async16(vgl + (size_t)(p * 32) * S_, Vt + (p * 32 + wave * 8) * 64);

  int cur = 0;
  for (int kt = 0; kt < nt; ++kt) {
    const bool more = (kt + 1 < nt);
    if (more) {
      for (int p = 0; p < 4; ++p)
        async16(kgl + (size_t)((kt + 1) * 64 + p * 16) * D_,
                Ks[cur ^ 1] + (p * 16 + wave * 4) * 128);
      asm volatile("s_waitcnt vmcnt(8)" ::: "memory");
    } else {
      asm volatile("s_waitcnt vmcnt(4)" ::: "memory");
    }
    __builtin_amdgcn_s_barrier();
    asm volatile("" ::: "memory");

    const bool active = (kt * 64 <= wmin + 31);
    if (active) {
      const bool diag = (kt * 64 + 63 > wmin);
      const __bf16* ksb = Ks[cur];
      for (int n = 0; n < 4; ++n) {
        f32x4 s0 = {}, s1 = {};
        __builtin_amdgcn_s_setprio(1);
#pragma unroll
        for (int kk = 0; kk < 4; ++kk) {
          bf16_8 kf = *(const bf16_8*)&ksb[(n * 16 + l16) * 128 + (((kk * 4 + quad) ^ l16) * 8)];
          s0 = mfma16(qf[0][kk], kf, s0);
          s1 = mfma16(qf[1][kk], kf, s1);
        }
        __builtin_amdgcn_s_setprio(0);
#pragma unroll
        for (int qs = 0; qs < 2; ++qs) {
          f32x4 sv = qs ? s1 : s0;
          for (int r = 0; r < 4; ++r) {
            float v = sv[r];
            if (diag) {
              int qr = wmin + qs * 16 + quad * 4 + r;
              if (kt * 64 + n * 16 + l16 > qr) v = -INFINITY;
            }
            float p = exp2f(v);
            lsum[qs][r] += p;
            Ps[wave][qs * 16 + quad * 4 + r][n * 16 + l16] = (__bf16)p;
          }
        }
      }
    }

    if (more) asm volatile("s_waitcnt vmcnt(4)" ::: "memory");
    else      asm volatile("s_waitcnt vmcnt(0)" ::: "memory");
    __builtin_amdgcn_s_barrier();
    asm volatile("" ::: "memory");

    if (active) {
      bf16_8 pf0[2], pf1[2];
      for (int qs = 0; qs < 2; ++qs) {
        pf0[qs] = *(const bf16_8*)&Ps[wave][qs * 16 + l16][quad * 8];
        pf1[qs] = *(const bf16_8*)&Ps[wave][qs * 16 + l16][32 + quad * 8];
      }
      __builtin_amdgcn_s_setprio(1);
#pragma unroll
      for (int nc = 0; nc < 8; ++nc) {
        bf16_8 vf0 = *(const bf16_8*)&Vt[(nc * 16 + l16) * 64 + ((quad ^ (l16 & 7)) * 8)];
        bf16_8 vf1 = *(const bf16_8*)&Vt[(nc * 16 + l16) * 64 + (((quad + 4) ^ (l16 & 7)) * 8)];
        oacc[0][nc] = mfma16(pf0[0], vf0, oacc[0][nc]);
        oacc[0][nc] = mfma16(pf1[0], vf1, oacc[0][nc]);
        oacc[1][nc] = mfma16(pf0[1], vf0, oacc[1][nc]);
        oacc[1][nc] = mfma16(pf1[1], vf1, oacc[1][nc]);
      }
      __builtin_amdgcn_s_setprio(0);
    }

    asm volatile("s_waitcnt lgkmcnt(0)" ::: "memory");
    __builtin_amdgcn_s_barrier();
    asm volatile("" ::: "memory");
    if (more)
      for (int p = 0; p < 4; ++p)
        async16(vgl + (size_t)(p * 32) * S_ + (size_t)(kt + 1) * 64,
                Vt + (p * 32 + wave * 8) * 64);
    cur ^= 1;
  }

  for (int qs = 0; qs < 2; ++qs)
    for (int r = 0; r < 4; ++r) {
      float l = lsum[qs][r];
      l += __shfl_xor(l, 1);
      l += __shfl_xor(l, 2);
      l += __shfl_xor(l, 4);
      l += __shfl_xor(l, 8);
      float rinv = 1.f / l;
      int qr = wmin + qs * 16 + quad * 4 + r;
      for (int nc = 0; nc < 8; ++nc)
        O[base + (size_t)qr * D_ + nc * 16 + l16] = (__bf16)(oacc[qs][nc][r] * rinv);
    }
}

extern "C" void kernel_launch(void* const* d_in, const int* in_sizes, int n_in,
                              void* d_out, int out_size, void* d_ws, size_t ws_size,
                              hipStream_t stream)
{
  const float* x    = (const float*)d_in[0];
  const float* fcos = (const float*)d_in[1];
  const float* fsin = (const float*)d_in[2];
  // d_in[3] = causal mask: implied by kernel structure, unused
  const float* wq   = (const float*)d_in[4];
  const float* wk   = (const float*)d_in[5];
  const float* wv   = (const float*)d_in[6];
  const float* wo   = (const float*)d_in[7];
  float* out = (float*)d_out;

  const size_t T = (size_t)B_ * S_ * D_;   // 8.39M elems
  const size_t W = (size_t)D_ * D_;        // 4.19M elems
  __bf16* xb  = (__bf16*)d_ws;  // x bf16; reused as attention-out
  __bf16* qw  = xb + T;
  __bf16* kw  = qw + T;
  __bf16* vt  = kw + T;
  __bf16* wqb = vt + T;
  __bf16* wkb = wqb + W;
  __bf16* wvb = wkb + W;
  __bf16* wob = wvb + W;
  __bf16* ow  = xb;

  const bool wb = ws_size >= (4 * T + 4 * W) * sizeof(__bf16);  // 100.7 MB
  const int W8 = (int)(W / 8);
  cvt_all<<<(wb ? 6 : 2) * W8 / 256, 256, 0, stream>>>(
      x, wq, wk, wv, wo, xb, wqb, wkb, wvb, wob);
  if (wb)
    qkv_gemm8<<<dim3(48, 16), 512, 0, stream>>>(
        xb, wqb, wkb, wvb, fcos, fsin, qw, kw, vt);
  else
    qkv_gemm<false><<<dim3(48, 32), 256, 0, stream>>>(
        xb, wq, wk, wv, nullptr, nullptr, nullptr, fcos, fsin, qw, kw, vt);
  attn_kernel<<<dim3(S_ / 128, B_ * H_), 256, 0, stream>>>(qw, kw, vt, ow);
  if (wb)
    out_gemm<true><<<dim3(16, 32), 256, 0, stream>>>(ow, nullptr, wob, out);
  else
    out_gemm<false><<<dim3(16, 32), 256, 0, stream>>>(ow, wo, nullptr, out);
}